// Round 12
// baseline (248.567 us; speedup 1.0000x reference)
//
#include <hip/hip_runtime.h>
#include <hip/hip_bf16.h>

#define E 128
#define F 128
#define O 64
#define K 8
#define BATCH 2048
#define NEWTON_IT 6

typedef __attribute__((ext_vector_type(8))) short bf8;     // 8 bf16 (4 VGPR)
typedef __attribute__((ext_vector_type(16))) float f16x;   // MFMA 32x32 accumulator
typedef __attribute__((ext_vector_type(2))) float f2;      // packed f32 (VOP3P)

typedef __attribute__((address_space(1))) const unsigned int g_u32;
typedef __attribute__((address_space(3))) unsigned int l_u32;

// ---------------------------------------------------------------------------
// Kernel A: M[k,o,x] = 0.5 * sum_y bil[k,x,y] * Q[k,o,y], truncated-bf16
// hi/lo split, packed per head as ONE contiguous 32 KB chunk:
//   head k: [hi: [16][64][8] shorts][lo: same]   (fragment-major, x=s*16+h*8+e)
// so kernel B can stage a whole head with a single linear DMA copy.
// ---------------------------------------------------------------------------
__global__ __launch_bounds__(256) void precompute_M(const float* __restrict__ Q,
                                                    const float* __restrict__ bil,
                                                    unsigned short* __restrict__ Mws) {
    int idx = blockIdx.x * 256 + threadIdx.x;   // ((kk*O + o)*E + x)
    int x  = idx & 127;
    int o  = (idx >> 7) & 63;
    int kk = idx >> 13;
    const float4* br = (const float4*)(bil + (size_t)(kk * E + x) * E);
    const float4* qr = (const float4*)(Q + (size_t)(kk * O + o) * E);
    float acc = 0.f;
#pragma unroll 8
    for (int y = 0; y < E / 4; ++y) {
        float4 bv = br[y], qv = qr[y];
        acc = fmaf(bv.x, qv.x, acc);
        acc = fmaf(bv.y, qv.y, acc);
        acc = fmaf(bv.z, qv.z, acc);
        acc = fmaf(bv.w, qv.w, acc);
    }
    float m = 0.5f * acc;
    unsigned um = __float_as_uint(m);
    float hi = __uint_as_float(um & 0xFFFF0000u);
    float lo = m - hi;
    int s = x >> 4, h = (x >> 3) & 1, e = x & 7;
    int local = (((s * 2 + h) * 64 + o) << 3) + e;      // 0..8191
    unsigned short* hp = Mws + (size_t)kk * 16384;      // head base (shorts)
    hp[local]        = (unsigned short)(um >> 16);
    hp[8192 + local] = (unsigned short)(__float_as_uint(lo) >> 16);
}

// split a,b into truncated-bf16 hi words + lo words, packed pairwise
#define SPLIT_PK(a, b, hw, lw)                                              \
    {                                                                       \
        unsigned ua = __float_as_uint(a), ub = __float_as_uint(b);          \
        float la = (a) - __uint_as_float(ua & 0xFFFF0000u);                 \
        float lb = (b) - __uint_as_float(ub & 0xFFFF0000u);                 \
        hw = (ua >> 16) | (ub & 0xFFFF0000u);                               \
        lw = (__float_as_uint(la) >> 16) | (__float_as_uint(lb) & 0xFFFF0000u); \
    }

__device__ __forceinline__ float fastrcp(float x) {
    float r = __builtin_amdgcn_rcpf(x);
    return r * __builtin_fmaf(-x, r, 2.0f);   // 1 NR step -> ~f32-exact
}

// ---------------------------------------------------------------------------
// Kernel B: one block per b; x loaded+split once. Per head: M already in LDS
// (prefetched async via global_load_lds during the PREVIOUS head's Newton ->
// zero VGPR round-trip, zero ds_writes, latency hidden under pure-VALU work);
// MFMA -> transpose C into the same buffer (M dead) -> Newton entmax -> out.
// LDS 32 KB -> 5 blocks/CU; launch_bounds(256,3) -> no spill.
// ---------------------------------------------------------------------------
__global__ __launch_bounds__(256, 3) void fused_entmax(
        const float* __restrict__ xg,
        const unsigned short* __restrict__ Mws,
        const float* __restrict__ values,
        float* __restrict__ out) {
    __shared__ float4 buf[2048];             // 32768 B: M-stage / z-tile (time-shared)
    float* lds = (float*)buf;
    unsigned short* ldsM = (unsigned short*)buf;

    int b = blockIdx.x;
    const float* xb = xg + (size_t)b * (F * E);

    int tid  = threadIdx.x;
    int w    = tid >> 6, l = tid & 63;
    int lo31 = l & 31;
    int hl   = l >> 5;                       // K-half: x-chunk 0 or 8
    int fcol = w * 32 + lo31;

    // ---- issue async DMA for head 0's M (overlaps the x load/split below) ----
#pragma unroll
    for (int i = 0; i < 8; ++i)
        __builtin_amdgcn_global_load_lds(
            (g_u32*)((const float4*)Mws + i * 256 + tid),
            (l_u32*)(&buf[i * 256 + tid]), 16, 0, 0);

    // ---- B operand once per block: x[fcol][s*16+hl*8 .. +8), split hi/lo ----
    bf8 Bh[8], Bl[8];
#pragma unroll
    for (int s = 0; s < 8; ++s) {
        const float* p = xb + (size_t)fcol * E + s * 16 + hl * 8;
        float4 v0 = *(const float4*)p;
        float4 v1 = *(const float4*)(p + 4);
        union { bf8 v; unsigned u[4]; } H, L;
        SPLIT_PK(v0.x, v0.y, H.u[0], L.u[0]);
        SPLIT_PK(v0.z, v0.w, H.u[1], L.u[1]);
        SPLIT_PK(v1.x, v1.y, H.u[2], L.u[2]);
        SPLIT_PK(v1.z, v1.w, H.u[3], L.u[3]);
        Bh[s] = H.v;
        Bl[s] = L.v;
    }

    int orow = tid >> 2;
    int q    = tid & 3;
    int rsw  = (orow & 7) << 2;              // read-side bank swizzle
    const f2 zero2 = {0.f, 0.f};

    __syncthreads();                         // drains DMA (vmcnt) + all waves

#pragma unroll 1
    for (int kh = 0; kh < K; ++kh) {
        // ---- MFMA K-loop: A-fragments from LDS (conflict-free b128) ----
        f16x acc0{}, acc1{};
#pragma unroll
        for (int s = 0; s < 8; ++s) {
            int base = ((s * 2 + hl) * 64) << 3;
            bf8 a0h = *(const bf8*)(ldsM + base + (lo31 << 3));
            bf8 a0l = *(const bf8*)(ldsM + 8192 + base + (lo31 << 3));
            bf8 a1h = *(const bf8*)(ldsM + base + ((lo31 + 32) << 3));
            bf8 a1l = *(const bf8*)(ldsM + 8192 + base + ((lo31 + 32) << 3));
            acc0 = __builtin_amdgcn_mfma_f32_32x32x16_bf16(a0l, Bh[s], acc0, 0, 0, 0);
            acc0 = __builtin_amdgcn_mfma_f32_32x32x16_bf16(a0h, Bl[s], acc0, 0, 0, 0);
            acc0 = __builtin_amdgcn_mfma_f32_32x32x16_bf16(a0h, Bh[s], acc0, 0, 0, 0);
            acc1 = __builtin_amdgcn_mfma_f32_32x32x16_bf16(a1l, Bh[s], acc1, 0, 0, 0);
            acc1 = __builtin_amdgcn_mfma_f32_32x32x16_bf16(a1h, Bl[s], acc1, 0, 0, 0);
            acc1 = __builtin_amdgcn_mfma_f32_32x32x16_bf16(a1h, Bh[s], acc1, 0, 0, 0);
        }
        __syncthreads();                     // all A-reads done; M now dead

        // ---- transpose C into lds[o][f ^ ((o&7)<<2)] (overwrites M) ----
#pragma unroll
        for (int r = 0; r < 16; ++r) {
            int ol = (r & 3) + ((r >> 2) << 3) + (hl << 2);
            int fs = fcol ^ ((ol & 7) << 2);
            lds[ol * 128 + fs]        = acc0[r];
            lds[(ol + 32) * 128 + fs] = acc1[r];
        }
        __syncthreads();

        // ---- load row orow as packed f2 (128 elems across 4-lane quad) ----
        f2 z2[16];
#pragma unroll
        for (int j = 0; j < 8; ++j) {
            float4 v = *(const float4*)&lds[orow * 128 + ((q * 4 + 16 * j) ^ rsw)];
            z2[2 * j]     = f2{v.x, v.y};
            z2[2 * j + 1] = f2{v.z, v.w};
        }
        __syncthreads();                     // all z-loads done; buffer free

        // ---- issue async DMA for next head's M (hides under Newton) ----
        if (kh < K - 1) {
            const float4* src = (const float4*)(Mws + (size_t)(kh + 1) * 16384);
#pragma unroll
            for (int i = 0; i < 8; ++i)
                __builtin_amdgcn_global_load_lds(
                    (g_u32*)(src + i * 256 + tid),
                    (l_u32*)(&buf[i * 256 + tid]), 16, 0, 0);
        }

        // ---- row max ----
        f2 mm0 = z2[0], mm1 = z2[1], mm2 = z2[2], mm3 = z2[3];
#pragma unroll
        for (int i = 4; i < 16; i += 4) {
            mm0 = __builtin_elementwise_max(mm0, z2[i]);
            mm1 = __builtin_elementwise_max(mm1, z2[i + 1]);
            mm2 = __builtin_elementwise_max(mm2, z2[i + 2]);
            mm3 = __builtin_elementwise_max(mm3, z2[i + 3]);
        }
        mm0 = __builtin_elementwise_max(__builtin_elementwise_max(mm0, mm1),
                                        __builtin_elementwise_max(mm2, mm3));
        float mx = fmaxf(mm0.x, mm0.y);
        mx = fmaxf(mx, __shfl_xor(mx, 1));
        mx = fmaxf(mx, __shfl_xor(mx, 2));

        // ---- Newton on f(t)=sum relu(z-t)^2-1 from t0=mx-1 (packed eval) ----
        float t = mx - 1.0f;
#pragma unroll
        for (int it = 0; it < NEWTON_IT; ++it) {
            f2 tt = {t, t};
            f2 sA = zero2, sB = zero2, lA = zero2, lB = zero2;
#pragma unroll
            for (int i = 0; i < 16; i += 2) {
                f2 d0 = __builtin_elementwise_max(z2[i] - tt, zero2);
                f2 d1 = __builtin_elementwise_max(z2[i + 1] - tt, zero2);
                sA = d0 * d0 + sA;           // v_pk_fma_f32
                sB = d1 * d1 + sB;
                lA += d0;                    // v_pk_add_f32
                lB += d1;
            }
            f2 sv = sA + sB;
            f2 lv = lA + lB;
            float fs = sv.x + sv.y;
            float sl = lv.x + lv.y;
            fs += __shfl_xor(fs, 1);
            fs += __shfl_xor(fs, 2);
            sl += __shfl_xor(sl, 1);
            sl += __shfl_xor(sl, 2);
            t += (fs - 1.0f) * 0.5f * fastrcp(sl);   // convex, from below
        }

        // ---- final eval: d^2 in place (packed), normalizer ----
        {
            f2 tt = {t, t};
            f2 nA = zero2, nB = zero2;
#pragma unroll
            for (int i = 0; i < 16; i += 2) {
                f2 d0 = __builtin_elementwise_max(z2[i] - tt, zero2);
                f2 d1 = __builtin_elementwise_max(z2[i + 1] - tt, zero2);
                d0 *= d0;                    // v_pk_mul_f32
                d1 *= d1;
                nA += d0;
                nB += d1;
                z2[i] = d0;
                z2[i + 1] = d1;
            }
            f2 nv = nA + nB;
            float sn = nv.x + nv.y;
            sn += __shfl_xor(sn, 1);
            sn += __shfl_xor(sn, 2);
            float inv = fastrcp(sn);

            // ---- scale by values, write out (packed muls) ----
            f2 iv = {inv, inv};
            const float* vr = values + (size_t)(kh * O + orow) * F;
            float* op = out + (((size_t)b * K + kh) * O + orow) * (size_t)F;
#pragma unroll
            for (int j = 0; j < 8; ++j) {
                int fb = q * 4 + 16 * j;
                float4 vv = *(const float4*)(vr + fb);
                f2 a = z2[2 * j] * iv;
                f2 c = z2[2 * j + 1] * iv;
                a *= f2{vv.x, vv.y};
                c *= f2{vv.z, vv.w};
                float4 ov = {a.x, a.y, c.x, c.y};
                *(float4*)(op + fb) = ov;
            }
        }

        if (kh < K - 1) __syncthreads();     // barrier drain (vmcnt 0) -> DMA landed
    }
}

extern "C" void kernel_launch(void* const* d_in, const int* in_sizes, int n_in,
                              void* d_out, int out_size, void* d_ws, size_t ws_size,
                              hipStream_t stream) {
    const float* x      = (const float*)d_in[0];   // [B, F, E]
    const float* Q      = (const float*)d_in[1];   // [K, O, E]
    const float* bil    = (const float*)d_in[2];   // [K, E, E]
    const float* values = (const float*)d_in[3];   // [K, O, F]
    float* out = (float*)d_out;                    // [B, K, O, F]

    unsigned short* Mws = (unsigned short*)d_ws;   // K heads x 32 KB (hi|lo)

    precompute_M<<<(K * O * E) / 256, 256, 0, stream>>>(Q, bil, Mws);
    fused_entmax<<<BATCH, 256, 0, stream>>>(x, Mws, values, out);
}

// Round 13
// 237.912 us; speedup vs baseline: 1.0448x; 1.0448x over previous
//
#include <hip/hip_runtime.h>
#include <hip/hip_bf16.h>

#define E 128
#define F 128
#define O 64
#define K 8
#define BATCH 2048
#define NEWTON_IT 6

typedef __attribute__((ext_vector_type(8))) short bf8;     // 8 bf16 (4 VGPR)
typedef __attribute__((ext_vector_type(16))) float f16x;   // MFMA 32x32 accumulator
typedef __attribute__((ext_vector_type(2))) float f2;      // packed f32 (VOP3P)

// ---------------------------------------------------------------------------
// Kernel A: M[k,o,x] = 0.5 * sum_y bil[k,x,y] * Q[k,o,y], truncated-bf16
// hi/lo split, packed per head as ONE contiguous 32 KB chunk:
//   head k: [hi: [16][64][8] shorts][lo: same]   (fragment-major, x=s*16+h*8+e)
// so kernel B can stage a whole head with a single linear float4 copy.
// ---------------------------------------------------------------------------
__global__ __launch_bounds__(256) void precompute_M(const float* __restrict__ Q,
                                                    const float* __restrict__ bil,
                                                    unsigned short* __restrict__ Mws) {
    int idx = blockIdx.x * 256 + threadIdx.x;   // ((kk*O + o)*E + x)
    int x  = idx & 127;
    int o  = (idx >> 7) & 63;
    int kk = idx >> 13;
    const float4* br = (const float4*)(bil + (size_t)(kk * E + x) * E);
    const float4* qr = (const float4*)(Q + (size_t)(kk * O + o) * E);
    float acc = 0.f;
#pragma unroll 8
    for (int y = 0; y < E / 4; ++y) {
        float4 bv = br[y], qv = qr[y];
        acc = fmaf(bv.x, qv.x, acc);
        acc = fmaf(bv.y, qv.y, acc);
        acc = fmaf(bv.z, qv.z, acc);
        acc = fmaf(bv.w, qv.w, acc);
    }
    float m = 0.5f * acc;
    unsigned um = __float_as_uint(m);
    float hi = __uint_as_float(um & 0xFFFF0000u);
    float lo = m - hi;
    int s = x >> 4, h = (x >> 3) & 1, e = x & 7;
    int local = (((s * 2 + h) * 64 + o) << 3) + e;      // 0..8191
    unsigned short* hp = Mws + (size_t)kk * 16384;      // head base (shorts)
    hp[local]        = (unsigned short)(um >> 16);
    hp[8192 + local] = (unsigned short)(__float_as_uint(lo) >> 16);
}

// split a,b into truncated-bf16 hi words + lo words, packed pairwise
#define SPLIT_PK(a, b, hw, lw)                                              \
    {                                                                       \
        unsigned ua = __float_as_uint(a), ub = __float_as_uint(b);          \
        float la = (a) - __uint_as_float(ua & 0xFFFF0000u);                 \
        float lb = (b) - __uint_as_float(ub & 0xFFFF0000u);                 \
        hw = (ua >> 16) | (ub & 0xFFFF0000u);                               \
        lw = (__float_as_uint(la) >> 16) | (__float_as_uint(lb) & 0xFFFF0000u); \
    }

__device__ __forceinline__ float fastrcp(float x) {
    float r = __builtin_amdgcn_rcpf(x);
    return r * __builtin_fmaf(-x, r, 2.0f);   // 1 NR step -> ~f32-exact
}

// ---------------------------------------------------------------------------
// Kernel B: one block per b; x loaded+split once (these regs serve as the
// MFMA *A* operand: A row = l&31 = f). Per head: stage M into LDS (sync copy,
// r11-validated), MFMA with B = M fragments from LDS -> C[f][o]: lane holds
// o = l&31 (+32), r-quads = 4 contiguous f -> transpose is 8 ds_write_b128
// (was 32 scalar b32). Same [o][f ^ ((o&7)<<2)] z-tile, packed-f32 Newton.
// LDS 32 KB -> 5 blocks/CU; launch_bounds(256,3) -> no spill.
// ---------------------------------------------------------------------------
__global__ __launch_bounds__(256, 3) void fused_entmax(
        const float* __restrict__ xg,
        const unsigned short* __restrict__ Mws,
        const float* __restrict__ values,
        float* __restrict__ out) {
    __shared__ float4 buf[2048];             // 32768 B: M-stage / z-tile (time-shared)
    float* lds = (float*)buf;
    unsigned short* ldsM = (unsigned short*)buf;

    int b = blockIdx.x;
    const float* xb = xg + (size_t)b * (F * E);

    int tid  = threadIdx.x;
    int w    = tid >> 6, l = tid & 63;
    int lo31 = l & 31;
    int hl   = l >> 5;                       // K-half: x-chunk 0 or 8
    int fcol = w * 32 + lo31;

    // ---- A operand once per block: x[fcol][s*16+hl*8 .. +8), split hi/lo ----
    bf8 Ah[8], Al[8];
#pragma unroll
    for (int s = 0; s < 8; ++s) {
        const float* p = xb + (size_t)fcol * E + s * 16 + hl * 8;
        float4 v0 = *(const float4*)p;
        float4 v1 = *(const float4*)(p + 4);
        union { bf8 v; unsigned u[4]; } H, L;
        SPLIT_PK(v0.x, v0.y, H.u[0], L.u[0]);
        SPLIT_PK(v0.z, v0.w, H.u[1], L.u[1]);
        SPLIT_PK(v1.x, v1.y, H.u[2], L.u[2]);
        SPLIT_PK(v1.z, v1.w, H.u[3], L.u[3]);
        Ah[s] = H.v;
        Al[s] = L.v;
    }

    int orow = tid >> 2;
    int q    = tid & 3;
    int rsw  = (orow & 7) << 2;              // read-side bank swizzle
    const f2 zero2 = {0.f, 0.f};

#pragma unroll 1
    for (int kh = 0; kh < K; ++kh) {
        // ---- stage head's M (32 KB) into LDS: linear coalesced copy ----
        if (kh) __syncthreads();             // prev head's z-loads done
        {
            const float4* src = (const float4*)(Mws + (size_t)kh * 16384);
#pragma unroll
            for (int i = 0; i < 8; ++i)
                buf[i * 256 + tid] = src[i * 256 + tid];
        }
        __syncthreads();

        // ---- MFMA K-loop: B = M fragments from LDS (conflict-free b128) ----
        // acc = x_hi*M_hi + x_hi*M_lo + x_lo*M_hi ; C[f][o], col = o = l&31
        f16x acc0{}, acc1{};
#pragma unroll
        for (int s = 0; s < 8; ++s) {
            int base = ((s * 2 + hl) * 64) << 3;
            bf8 b0h = *(const bf8*)(ldsM + base + (lo31 << 3));
            bf8 b0l = *(const bf8*)(ldsM + 8192 + base + (lo31 << 3));
            bf8 b1h = *(const bf8*)(ldsM + base + ((lo31 + 32) << 3));
            bf8 b1l = *(const bf8*)(ldsM + 8192 + base + ((lo31 + 32) << 3));
            acc0 = __builtin_amdgcn_mfma_f32_32x32x16_bf16(Al[s], b0h, acc0, 0, 0, 0);
            acc0 = __builtin_amdgcn_mfma_f32_32x32x16_bf16(Ah[s], b0l, acc0, 0, 0, 0);
            acc0 = __builtin_amdgcn_mfma_f32_32x32x16_bf16(Ah[s], b0h, acc0, 0, 0, 0);
            acc1 = __builtin_amdgcn_mfma_f32_32x32x16_bf16(Al[s], b1h, acc1, 0, 0, 0);
            acc1 = __builtin_amdgcn_mfma_f32_32x32x16_bf16(Ah[s], b1l, acc1, 0, 0, 0);
            acc1 = __builtin_amdgcn_mfma_f32_32x32x16_bf16(Ah[s], b1h, acc1, 0, 0, 0);
        }
        __syncthreads();                     // all B-reads done; M now dead

        // ---- vectorized transpose: r-quad = 4 contiguous f -> b128 writes ----
        // C row decode: f_local = (r&3) + 8*(r>>2) + 4*hl ; global f = w*32 + ..
#pragma unroll
        for (int g = 0; g < 4; ++g) {
            int fc = w * 32 + 8 * g + 4 * hl;            // 4-aligned f chunk
            float4 w0 = {acc0[4 * g], acc0[4 * g + 1], acc0[4 * g + 2], acc0[4 * g + 3]};
            float4 w1 = {acc1[4 * g], acc1[4 * g + 1], acc1[4 * g + 2], acc1[4 * g + 3]};
            *(float4*)&lds[lo31 * 128 + (fc ^ ((lo31 & 7) << 2))]              = w0;
            *(float4*)&lds[(lo31 + 32) * 128 + (fc ^ (((lo31 + 32) & 7) << 2))] = w1;
        }
        __syncthreads();

        // ---- load row orow as packed f2 (128 elems across 4-lane quad) ----
        f2 z2[16];
#pragma unroll
        for (int j = 0; j < 8; ++j) {
            float4 v = *(const float4*)&lds[orow * 128 + ((q * 4 + 16 * j) ^ rsw)];
            z2[2 * j]     = f2{v.x, v.y};
            z2[2 * j + 1] = f2{v.z, v.w};
        }

        // ---- row max ----
        f2 mm0 = z2[0], mm1 = z2[1], mm2 = z2[2], mm3 = z2[3];
#pragma unroll
        for (int i = 4; i < 16; i += 4) {
            mm0 = __builtin_elementwise_max(mm0, z2[i]);
            mm1 = __builtin_elementwise_max(mm1, z2[i + 1]);
            mm2 = __builtin_elementwise_max(mm2, z2[i + 2]);
            mm3 = __builtin_elementwise_max(mm3, z2[i + 3]);
        }
        mm0 = __builtin_elementwise_max(__builtin_elementwise_max(mm0, mm1),
                                        __builtin_elementwise_max(mm2, mm3));
        float mx = fmaxf(mm0.x, mm0.y);
        mx = fmaxf(mx, __shfl_xor(mx, 1));
        mx = fmaxf(mx, __shfl_xor(mx, 2));

        // ---- Newton on f(t)=sum relu(z-t)^2-1 from t0=mx-1 (packed eval) ----
        float t = mx - 1.0f;
#pragma unroll
        for (int it = 0; it < NEWTON_IT; ++it) {
            f2 tt = {t, t};
            f2 sA = zero2, sB = zero2, lA = zero2, lB = zero2;
#pragma unroll
            for (int i = 0; i < 16; i += 2) {
                f2 d0 = __builtin_elementwise_max(z2[i] - tt, zero2);
                f2 d1 = __builtin_elementwise_max(z2[i + 1] - tt, zero2);
                sA = d0 * d0 + sA;           // v_pk_fma_f32
                sB = d1 * d1 + sB;
                lA += d0;                    // v_pk_add_f32
                lB += d1;
            }
            f2 sv = sA + sB;
            f2 lv = lA + lB;
            float fs = sv.x + sv.y;
            float sl = lv.x + lv.y;
            fs += __shfl_xor(fs, 1);
            fs += __shfl_xor(fs, 2);
            sl += __shfl_xor(sl, 1);
            sl += __shfl_xor(sl, 2);
            t += (fs - 1.0f) * 0.5f * fastrcp(sl);   // convex, from below
        }

        // ---- final eval: d^2 in place (packed), normalizer ----
        {
            f2 tt = {t, t};
            f2 nA = zero2, nB = zero2;
#pragma unroll
            for (int i = 0; i < 16; i += 2) {
                f2 d0 = __builtin_elementwise_max(z2[i] - tt, zero2);
                f2 d1 = __builtin_elementwise_max(z2[i + 1] - tt, zero2);
                d0 *= d0;                    // v_pk_mul_f32
                d1 *= d1;
                nA += d0;
                nB += d1;
                z2[i] = d0;
                z2[i + 1] = d1;
            }
            f2 nv = nA + nB;
            float sn = nv.x + nv.y;
            sn += __shfl_xor(sn, 1);
            sn += __shfl_xor(sn, 2);
            float inv = fastrcp(sn);

            // ---- scale by values, write out (packed muls) ----
            f2 iv = {inv, inv};
            const float* vr = values + (size_t)(kh * O + orow) * F;
            float* op = out + (((size_t)b * K + kh) * O + orow) * (size_t)F;
#pragma unroll
            for (int j = 0; j < 8; ++j) {
                int fb = q * 4 + 16 * j;
                float4 vv = *(const float4*)(vr + fb);
                f2 a = z2[2 * j] * iv;
                f2 c = z2[2 * j + 1] * iv;
                a *= f2{vv.x, vv.y};
                c *= f2{vv.z, vv.w};
                float4 ov = {a.x, a.y, c.x, c.y};
                *(float4*)(op + fb) = ov;
            }
        }
    }
}

extern "C" void kernel_launch(void* const* d_in, const int* in_sizes, int n_in,
                              void* d_out, int out_size, void* d_ws, size_t ws_size,
                              hipStream_t stream) {
    const float* x      = (const float*)d_in[0];   // [B, F, E]
    const float* Q      = (const float*)d_in[1];   // [K, O, E]
    const float* bil    = (const float*)d_in[2];   // [K, E, E]
    const float* values = (const float*)d_in[3];   // [K, O, F]
    float* out = (float*)d_out;                    // [B, K, O, F]

    unsigned short* Mws = (unsigned short*)d_ws;   // K heads x 32 KB (hi|lo)

    precompute_M<<<(K * O * E) / 256, 256, 0, stream>>>(Q, bil, Mws);
    fused_entmax<<<BATCH, 256, 0, stream>>>(x, Mws, values, out);
}

// Round 14
// 233.399 us; speedup vs baseline: 1.0650x; 1.0193x over previous
//
#include <hip/hip_runtime.h>
#include <hip/hip_bf16.h>

#define E 128
#define F 128
#define O 64
#define K 8
#define BATCH 2048
#define NEWTON_IT 6

typedef __attribute__((ext_vector_type(8))) short bf8;     // 8 bf16 (4 VGPR)
typedef __attribute__((ext_vector_type(16))) float f16x;   // MFMA 32x32 accumulator
typedef __attribute__((ext_vector_type(2))) float f2;      // packed f32 (VOP3P)

typedef __attribute__((address_space(1))) const unsigned int g_u32;
typedef __attribute__((address_space(3))) unsigned int l_u32;

// ---------------------------------------------------------------------------
// Kernel A: M[k,o,x] = 0.5 * sum_y bil[k,x,y] * Q[k,o,y], truncated-bf16
// hi/lo split, packed per head as ONE contiguous 32 KB chunk:
//   head k: [hi: [16][64][8] shorts][lo: same]   (fragment-major, x=s*16+h*8+e)
// so kernel B can stage a whole head with a single linear DMA copy.
// ---------------------------------------------------------------------------
__global__ __launch_bounds__(256) void precompute_M(const float* __restrict__ Q,
                                                    const float* __restrict__ bil,
                                                    unsigned short* __restrict__ Mws) {
    int idx = blockIdx.x * 256 + threadIdx.x;   // ((kk*O + o)*E + x)
    int x  = idx & 127;
    int o  = (idx >> 7) & 63;
    int kk = idx >> 13;
    const float4* br = (const float4*)(bil + (size_t)(kk * E + x) * E);
    const float4* qr = (const float4*)(Q + (size_t)(kk * O + o) * E);
    float acc = 0.f;
#pragma unroll 8
    for (int y = 0; y < E / 4; ++y) {
        float4 bv = br[y], qv = qr[y];
        acc = fmaf(bv.x, qv.x, acc);
        acc = fmaf(bv.y, qv.y, acc);
        acc = fmaf(bv.z, qv.z, acc);
        acc = fmaf(bv.w, qv.w, acc);
    }
    float m = 0.5f * acc;
    unsigned um = __float_as_uint(m);
    float hi = __uint_as_float(um & 0xFFFF0000u);
    float lo = m - hi;
    int s = x >> 4, h = (x >> 3) & 1, e = x & 7;
    int local = (((s * 2 + h) * 64 + o) << 3) + e;      // 0..8191
    unsigned short* hp = Mws + (size_t)kk * 16384;      // head base (shorts)
    hp[local]        = (unsigned short)(um >> 16);
    hp[8192 + local] = (unsigned short)(__float_as_uint(lo) >> 16);
}

// split a,b into truncated-bf16 hi words + lo words, packed pairwise
#define SPLIT_PK(a, b, hw, lw)                                              \
    {                                                                       \
        unsigned ua = __float_as_uint(a), ub = __float_as_uint(b);          \
        float la = (a) - __uint_as_float(ua & 0xFFFF0000u);                 \
        float lb = (b) - __uint_as_float(ub & 0xFFFF0000u);                 \
        hw = (ua >> 16) | (ub & 0xFFFF0000u);                               \
        lw = (__float_as_uint(la) >> 16) | (__float_as_uint(lb) & 0xFFFF0000u); \
    }

__device__ __forceinline__ float fastrcp(float x) {
    float r = __builtin_amdgcn_rcpf(x);
    return r * __builtin_fmaf(-x, r, 2.0f);   // 1 NR step -> ~f32-exact
}

// ---------------------------------------------------------------------------
// Kernel B: one block per b; x loaded+split once (regs = MFMA A operand,
// A row = l&31 = f). Per head: stage M into LDS via global_load_lds DMA
// (no VGPR round-trip, no ds_writes; the following __syncthreads drains
// vmcnt -- r12-verified semantics), MFMA (setprio-wrapped) with B = M
// fragments -> C[f][o] -> b128 transpose into the same buffer (M dead) ->
// packed-f32 Newton entmax -> out. LDS 32 KB -> 5 blocks/CU; (256,3) cap
// keeps the allocator spill-free (rounds 6/7 lesson).
// ---------------------------------------------------------------------------
__global__ __launch_bounds__(256, 3) void fused_entmax(
        const float* __restrict__ xg,
        const unsigned short* __restrict__ Mws,
        const float* __restrict__ values,
        float* __restrict__ out) {
    __shared__ float4 buf[2048];             // 32768 B: M-stage / z-tile (time-shared)
    float* lds = (float*)buf;
    unsigned short* ldsM = (unsigned short*)buf;

    int b = blockIdx.x;
    const float* xb = xg + (size_t)b * (F * E);

    int tid  = threadIdx.x;
    int w    = tid >> 6, l = tid & 63;
    int lo31 = l & 31;
    int hl   = l >> 5;                       // K-half: x-chunk 0 or 8
    int fcol = w * 32 + lo31;

    // ---- issue DMA for head 0's M (overlaps the x load/split below) ----
#pragma unroll
    for (int i = 0; i < 8; ++i)
        __builtin_amdgcn_global_load_lds(
            (g_u32*)((const float4*)Mws + i * 256 + tid),
            (l_u32*)(&buf[i * 256 + tid]), 16, 0, 0);

    // ---- A operand once per block: x[fcol][s*16+hl*8 .. +8), split hi/lo ----
    bf8 Ah[8], Al[8];
#pragma unroll
    for (int s = 0; s < 8; ++s) {
        const float* p = xb + (size_t)fcol * E + s * 16 + hl * 8;
        float4 v0 = *(const float4*)p;
        float4 v1 = *(const float4*)(p + 4);
        union { bf8 v; unsigned u[4]; } H, L;
        SPLIT_PK(v0.x, v0.y, H.u[0], L.u[0]);
        SPLIT_PK(v0.z, v0.w, H.u[1], L.u[1]);
        SPLIT_PK(v1.x, v1.y, H.u[2], L.u[2]);
        SPLIT_PK(v1.z, v1.w, H.u[3], L.u[3]);
        Ah[s] = H.v;
        Al[s] = L.v;
    }

    int orow = tid >> 2;
    int q    = tid & 3;
    int rsw  = (orow & 7) << 2;              // read-side bank swizzle
    const f2 zero2 = {0.f, 0.f};

#pragma unroll 1
    for (int kh = 0; kh < K; ++kh) {
        if (kh) {
            __syncthreads();                 // WAR: prev head's z-loads done
            const float4* src = (const float4*)(Mws + (size_t)kh * 16384);
#pragma unroll
            for (int i = 0; i < 8; ++i)
                __builtin_amdgcn_global_load_lds(
                    (g_u32*)(src + i * 256 + tid),
                    (l_u32*)(&buf[i * 256 + tid]), 16, 0, 0);
        }
        __syncthreads();                     // drains vmcnt -> M landed

        // ---- MFMA K-loop: B = M fragments from LDS (conflict-free b128) ----
        // acc = x_hi*M_hi + x_hi*M_lo + x_lo*M_hi ; C[f][o], col = o = l&31
        f16x acc0{}, acc1{};
        __builtin_amdgcn_s_setprio(1);
#pragma unroll
        for (int s = 0; s < 8; ++s) {
            int base = ((s * 2 + hl) * 64) << 3;
            bf8 b0h = *(const bf8*)(ldsM + base + (lo31 << 3));
            bf8 b0l = *(const bf8*)(ldsM + 8192 + base + (lo31 << 3));
            bf8 b1h = *(const bf8*)(ldsM + base + ((lo31 + 32) << 3));
            bf8 b1l = *(const bf8*)(ldsM + 8192 + base + ((lo31 + 32) << 3));
            acc0 = __builtin_amdgcn_mfma_f32_32x32x16_bf16(Al[s], b0h, acc0, 0, 0, 0);
            acc0 = __builtin_amdgcn_mfma_f32_32x32x16_bf16(Ah[s], b0l, acc0, 0, 0, 0);
            acc0 = __builtin_amdgcn_mfma_f32_32x32x16_bf16(Ah[s], b0h, acc0, 0, 0, 0);
            acc1 = __builtin_amdgcn_mfma_f32_32x32x16_bf16(Al[s], b1h, acc1, 0, 0, 0);
            acc1 = __builtin_amdgcn_mfma_f32_32x32x16_bf16(Ah[s], b1l, acc1, 0, 0, 0);
            acc1 = __builtin_amdgcn_mfma_f32_32x32x16_bf16(Ah[s], b1h, acc1, 0, 0, 0);
        }
        __builtin_amdgcn_s_setprio(0);
        __syncthreads();                     // all B-reads done; M now dead

        // ---- vectorized transpose: r-quad = 4 contiguous f -> b128 writes ----
        // C row decode: f_local = (r&3) + 8*(r>>2) + 4*hl ; global f = w*32 + ..
#pragma unroll
        for (int g = 0; g < 4; ++g) {
            int fc = w * 32 + 8 * g + 4 * hl;            // 4-aligned f chunk
            float4 w0 = {acc0[4 * g], acc0[4 * g + 1], acc0[4 * g + 2], acc0[4 * g + 3]};
            float4 w1 = {acc1[4 * g], acc1[4 * g + 1], acc1[4 * g + 2], acc1[4 * g + 3]};
            *(float4*)&lds[lo31 * 128 + (fc ^ ((lo31 & 7) << 2))]              = w0;
            *(float4*)&lds[(lo31 + 32) * 128 + (fc ^ (((lo31 + 32) & 7) << 2))] = w1;
        }
        __syncthreads();

        // ---- load row orow as packed f2 (128 elems across 4-lane quad) ----
        f2 z2[16];
#pragma unroll
        for (int j = 0; j < 8; ++j) {
            float4 v = *(const float4*)&lds[orow * 128 + ((q * 4 + 16 * j) ^ rsw)];
            z2[2 * j]     = f2{v.x, v.y};
            z2[2 * j + 1] = f2{v.z, v.w};
        }

        // ---- row max ----
        f2 mm0 = z2[0], mm1 = z2[1], mm2 = z2[2], mm3 = z2[3];
#pragma unroll
        for (int i = 4; i < 16; i += 4) {
            mm0 = __builtin_elementwise_max(mm0, z2[i]);
            mm1 = __builtin_elementwise_max(mm1, z2[i + 1]);
            mm2 = __builtin_elementwise_max(mm2, z2[i + 2]);
            mm3 = __builtin_elementwise_max(mm3, z2[i + 3]);
        }
        mm0 = __builtin_elementwise_max(__builtin_elementwise_max(mm0, mm1),
                                        __builtin_elementwise_max(mm2, mm3));
        float mx = fmaxf(mm0.x, mm0.y);
        mx = fmaxf(mx, __shfl_xor(mx, 1));
        mx = fmaxf(mx, __shfl_xor(mx, 2));

        // ---- Newton on f(t)=sum relu(z-t)^2-1 from t0=mx-1 (packed eval) ----
        float t = mx - 1.0f;
#pragma unroll
        for (int it = 0; it < NEWTON_IT; ++it) {
            f2 tt = {t, t};
            f2 sA = zero2, sB = zero2, lA = zero2, lB = zero2;
#pragma unroll
            for (int i = 0; i < 16; i += 2) {
                f2 d0 = __builtin_elementwise_max(z2[i] - tt, zero2);
                f2 d1 = __builtin_elementwise_max(z2[i + 1] - tt, zero2);
                sA = d0 * d0 + sA;           // v_pk_fma_f32
                sB = d1 * d1 + sB;
                lA += d0;                    // v_pk_add_f32
                lB += d1;
            }
            f2 sv = sA + sB;
            f2 lv = lA + lB;
            float fs = sv.x + sv.y;
            float sl = lv.x + lv.y;
            fs += __shfl_xor(fs, 1);
            fs += __shfl_xor(fs, 2);
            sl += __shfl_xor(sl, 1);
            sl += __shfl_xor(sl, 2);
            t += (fs - 1.0f) * 0.5f * fastrcp(sl);   // convex, from below
        }

        // ---- final eval: d^2 in place (packed), normalizer ----
        {
            f2 tt = {t, t};
            f2 nA = zero2, nB = zero2;
#pragma unroll
            for (int i = 0; i < 16; i += 2) {
                f2 d0 = __builtin_elementwise_max(z2[i] - tt, zero2);
                f2 d1 = __builtin_elementwise_max(z2[i + 1] - tt, zero2);
                d0 *= d0;                    // v_pk_mul_f32
                d1 *= d1;
                nA += d0;
                nB += d1;
                z2[i] = d0;
                z2[i + 1] = d1;
            }
            f2 nv = nA + nB;
            float sn = nv.x + nv.y;
            sn += __shfl_xor(sn, 1);
            sn += __shfl_xor(sn, 2);
            float inv = fastrcp(sn);

            // ---- scale by values, write out (packed muls) ----
            f2 iv = {inv, inv};
            const float* vr = values + (size_t)(kh * O + orow) * F;
            float* op = out + (((size_t)b * K + kh) * O + orow) * (size_t)F;
#pragma unroll
            for (int j = 0; j < 8; ++j) {
                int fb = q * 4 + 16 * j;
                float4 vv = *(const float4*)(vr + fb);
                f2 a = z2[2 * j] * iv;
                f2 c = z2[2 * j + 1] * iv;
                a *= f2{vv.x, vv.y};
                c *= f2{vv.z, vv.w};
                float4 ov = {a.x, a.y, c.x, c.y};
                *(float4*)(op + fb) = ov;
            }
        }
    }
}

extern "C" void kernel_launch(void* const* d_in, const int* in_sizes, int n_in,
                              void* d_out, int out_size, void* d_ws, size_t ws_size,
                              hipStream_t stream) {
    const float* x      = (const float*)d_in[0];   // [B, F, E]
    const float* Q      = (const float*)d_in[1];   // [K, O, E]
    const float* bil    = (const float*)d_in[2];   // [K, E, E]
    const float* values = (const float*)d_in[3];   // [K, O, F]
    float* out = (float*)d_out;                    // [B, K, O, F]

    unsigned short* Mws = (unsigned short*)d_ws;   // K heads x 32 KB (hi|lo)

    precompute_M<<<(K * O * E) / 256, 256, 0, stream>>>(Q, bil, Mws);
    fused_entmax<<<BATCH, 256, 0, stream>>>(x, Mws, values, out);
}